// Round 3
// baseline (2212.628 us; speedup 1.0000x reference)
//
#include <hip/hip_runtime.h>

// RNNDoubleStacked: P=4096 particles, F=128 max features (ragged), H=128 hidden.
// Phase A (net1_kernel): per-particle tanh RNN, one block/particle, W_hh1 rows in
//   VGPRs, h double-buffered in LDS (1 barrier/step), early exit at t==len.
//   Tail fuses U[p] = h1[p] @ W_ih2^T + b_ih2 + b_hh2 into d_ws.
// Phase B (net2_kernel): single block, 256 threads = 4 waves (1 wave/SIMD — R2
//   post-mortem showed 8 waves round-robin on 4 SIMDs stretched the latency
//   chain ~2x). Row r = wv*32 + (lane>>1); q=lane&1 does a 64-elem half-dot
//   from 64 VGPRs of W_hh2; h reads are 2-unique-addr b128 broadcasts (free);
//   one quad-perm shfl_xor(1) combines halves; 2-deep U prefetch covers the
//   cross-XCD/HBM latency of U rows; 1 barrier/step.

constexpr int PN = 4096;
constexpr int FN = 128;
constexpr int HN = 128;

__device__ __forceinline__ float fast_tanh(float x) {
    // tanh(x) = 1 - 2/(exp(2x)+1); correct +-1 limits via __expf saturation.
    float e = __expf(2.0f * x);
    return 1.0f - 2.0f / (e + 1.0f);
}

__global__ __launch_bounds__(128) void net1_kernel(
    const float* __restrict__ event,
    const int*   __restrict__ lengths,
    const float* __restrict__ W_ih1,
    const float* __restrict__ W_hh1,
    const float* __restrict__ b_ih1,
    const float* __restrict__ b_hh1,
    const float* __restrict__ W_ih2,
    const float* __restrict__ b_ih2,
    const float* __restrict__ b_hh2,
    float* __restrict__ U)
{
    const int p = blockIdx.x;
    const int i = threadIdx.x;                 // output row 0..127

    __shared__ float h[2][HN];                 // double-buffered hidden state
    __shared__ float ev[FN];                   // this particle's input sequence

    ev[i]   = event[p * FN + i];               // coalesced (event is [P,F,1])
    h[0][i] = 0.0f;

    // W_hh1 row i in registers (128 VGPRs) — reused across all steps.
    float w[HN];
    {
        const float4* wrow = reinterpret_cast<const float4*>(W_hh1 + i * HN);
        #pragma unroll
        for (int k = 0; k < HN / 4; ++k) {
            float4 v = wrow[k];
            w[4*k+0] = v.x; w[4*k+1] = v.y; w[4*k+2] = v.z; w[4*k+3] = v.w;
        }
    }
    const float wx   = W_ih1[i];               // W_ih1 is [H,1]
    const float bias = b_ih1[i] + b_hh1[i];
    const int   len  = lengths[p];             // uniform across block, in [1,127)

    __syncthreads();

    // Reference masks updates at t >= len (h frozen) -> just stop at len.
    for (int t = 0; t < len; ++t) {
        const int cur = t & 1;
        const float x = ev[t];                 // LDS broadcast
        float a0 = fmaf(wx, x, bias), a1 = 0.f, a2 = 0.f, a3 = 0.f;
        const float4* h4 = reinterpret_cast<const float4*>(h[cur]);
        #pragma unroll
        for (int k = 0; k < HN / 4; ++k) {
            float4 hv = h4[k];                 // same addr all lanes -> broadcast
            a0 = fmaf(w[4*k+0], hv.x, a0);
            a1 = fmaf(w[4*k+1], hv.y, a1);
            a2 = fmaf(w[4*k+2], hv.z, a2);
            a3 = fmaf(w[4*k+3], hv.w, a3);
        }
        h[cur ^ 1][i] = fast_tanh((a0 + a1) + (a2 + a3));
        __syncthreads();                       // single barrier: dbuf makes W/R safe
    }

    // Tail: U[p][i] = h1 . W_ih2_row_i + b_ih2[i] + b_hh2[i]  (hoisted out of net2)
    {
        const float4* h4 = reinterpret_cast<const float4*>(h[len & 1]);
        const float4* w2 = reinterpret_cast<const float4*>(W_ih2 + i * HN);
        float a0 = b_ih2[i] + b_hh2[i], a1 = 0.f, a2 = 0.f, a3 = 0.f;
        #pragma unroll
        for (int k = 0; k < HN / 4; ++k) {
            float4 hv = h4[k];
            float4 wv = w2[k];
            a0 = fmaf(wv.x, hv.x, a0);
            a1 = fmaf(wv.y, hv.y, a1);
            a2 = fmaf(wv.z, hv.z, a2);
            a3 = fmaf(wv.w, hv.w, a3);
        }
        U[p * HN + i] = (a0 + a1) + (a2 + a3); // coalesced
    }
}

__global__ __launch_bounds__(256) void net2_kernel(
    const float* __restrict__ U,
    const float* __restrict__ W_hh2,
    float* __restrict__ out)
{
    const int tid  = threadIdx.x;
    const int wv   = tid >> 6;                 // wave 0..3 (one per SIMD)
    const int lane = tid & 63;
    const int q    = lane & 1;                 // half of the dot: 0..1
    const int oi   = (wv << 5) + (lane >> 1);  // output row 0..127

    __shared__ float h[2][HN];                 // double-buffered hidden state

    // W_hh2[oi][q*64 .. q*64+64) in registers (64 VGPRs).
    float w[64];
    {
        const float4* ws = reinterpret_cast<const float4*>(W_hh2 + oi * HN + q * 64);
        #pragma unroll
        for (int k = 0; k < 16; ++k) {
            float4 v = ws[k];
            w[4*k+0] = v.x; w[4*k+1] = v.y; w[4*k+2] = v.z; w[4*k+3] = v.w;
        }
    }

    if (tid < HN) h[0][tid] = 0.0f;
    __syncthreads();

    const float* Up = U + oi;
    float u0 = Up[0];                          // U row 0 (for step 0)
    float u1 = Up[HN];                         // U row 1 (for step 1)

    for (int p = 0; p < PN; ++p) {
        const int cur = p & 1;
        const float u_cur = u0;
        u0 = u1;                               // rotate the 2-deep prefetch pipe
        const int pn = (p + 2 < PN) ? (p + 2) : (PN - 1);
        u1 = Up[pn * HN];                      // issued 2 steps ahead of use

        // h reads: q=0 lanes broadcast h[0..63], q=1 lanes h[64..127] — 2 unique
        // addresses per ds_read_b128 (2-way aliasing is free on 32 banks).
        const float4* h4 = reinterpret_cast<const float4*>(&h[cur][q * 64]);
        float a0 = 0.f, a1 = 0.f, a2 = 0.f, a3 = 0.f;
        #pragma unroll
        for (int k = 0; k < 16; ++k) {
            float4 hv = h4[k];
            a0 = fmaf(w[4*k+0], hv.x, a0);
            a1 = fmaf(w[4*k+1], hv.y, a1);
            a2 = fmaf(w[4*k+2], hv.z, a2);
            a3 = fmaf(w[4*k+3], hv.w, a3);
        }
        float s = (a0 + a1) + (a2 + a3);
        s += __shfl_xor(s, 1);                 // combine halves (quad-perm DPP)
        if (q == 0) h[cur ^ 1][oi] = fast_tanh(s + u_cur);
        __syncthreads();                       // single barrier: dbuf makes W/R safe
    }

    if (tid < HN) out[tid] = h[PN & 1][tid];   // PN even -> result in h[0]
}

extern "C" void kernel_launch(void* const* d_in, const int* in_sizes, int n_in,
                              void* d_out, int out_size, void* d_ws, size_t ws_size,
                              hipStream_t stream)
{
    const float* event   = (const float*)d_in[0];
    const int*   lengths = (const int*)  d_in[1];
    const float* W_ih1   = (const float*)d_in[2];
    const float* W_hh1   = (const float*)d_in[3];
    const float* b_ih1   = (const float*)d_in[4];
    const float* b_hh1   = (const float*)d_in[5];
    const float* W_ih2   = (const float*)d_in[6];
    const float* W_hh2   = (const float*)d_in[7];
    const float* b_ih2   = (const float*)d_in[8];
    const float* b_hh2   = (const float*)d_in[9];
    float* out = (float*)d_out;                // 128 floats
    float* U   = (float*)d_ws;                 // PN*HN floats = 2 MB scratch

    hipLaunchKernelGGL(net1_kernel, dim3(PN), dim3(HN), 0, stream,
                       event, lengths, W_ih1, W_hh1, b_ih1, b_hh1,
                       W_ih2, b_ih2, b_hh2, U);
    hipLaunchKernelGGL(net2_kernel, dim3(1), dim3(256), 0, stream,
                       U, W_hh2, out);
}

// Round 4
// 2024.776 us; speedup vs baseline: 1.0928x; 1.0928x over previous
//
#include <hip/hip_runtime.h>

// RNNDoubleStacked: P=4096 particles, F=128 max features (ragged), H=128 hidden.
// Phase A (net1_kernel): unchanged from R2/R3 (one block/particle, W row in VGPRs,
//   h dbuf in LDS, early exit at len; tail writes U = h1@W_ih2^T + biases).
// Phase B (net2_kernel): R3 post-mortem showed the step cost is LDS-pipe
//   throughput: 64 ds_read_b128/step (~768 cyc) because every FMA pulled its
//   h operand from LDS. New layout adds register reuse: lane = (og, jg) with
//   og = output-group (4 outputs), jg = inner-group (16-float slice of h).
//   Each lane reads 4 b128 (16 floats) and feeds 4 FMAs per float -> only
//   16 ds_read_b128/step total. Reads XOR-rotated (rotation baked into the
//   weight load order, so all reg indices are compile-time) -> conflict-free.
//   3-stage reduce-scatter (shfl_xor 4/2/1) leaves ONE output per lane ->
//   one tanh per lane, 16 conflict-free b32 writes per wave, 1 barrier/step.

constexpr int PN = 4096;
constexpr int FN = 128;
constexpr int HN = 128;

__device__ __forceinline__ float fast_tanh(float x) {
    // tanh(x) = 1 - 2/(exp(2x)+1); correct +-1 limits via __expf saturation.
    float e = __expf(2.0f * x);
    return 1.0f - 2.0f / (e + 1.0f);
}

__global__ __launch_bounds__(128) void net1_kernel(
    const float* __restrict__ event,
    const int*   __restrict__ lengths,
    const float* __restrict__ W_ih1,
    const float* __restrict__ W_hh1,
    const float* __restrict__ b_ih1,
    const float* __restrict__ b_hh1,
    const float* __restrict__ W_ih2,
    const float* __restrict__ b_ih2,
    const float* __restrict__ b_hh2,
    float* __restrict__ U)
{
    const int p = blockIdx.x;
    const int i = threadIdx.x;                 // output row 0..127

    __shared__ float h[2][HN];                 // double-buffered hidden state
    __shared__ float ev[FN];                   // this particle's input sequence

    ev[i]   = event[p * FN + i];               // coalesced (event is [P,F,1])
    h[0][i] = 0.0f;

    // W_hh1 row i in registers (128 VGPRs) — reused across all steps.
    float w[HN];
    {
        const float4* wrow = reinterpret_cast<const float4*>(W_hh1 + i * HN);
        #pragma unroll
        for (int k = 0; k < HN / 4; ++k) {
            float4 v = wrow[k];
            w[4*k+0] = v.x; w[4*k+1] = v.y; w[4*k+2] = v.z; w[4*k+3] = v.w;
        }
    }
    const float wx   = W_ih1[i];               // W_ih1 is [H,1]
    const float bias = b_ih1[i] + b_hh1[i];
    const int   len  = lengths[p];             // uniform across block, in [1,127)

    __syncthreads();

    // Reference masks updates at t >= len (h frozen) -> just stop at len.
    for (int t = 0; t < len; ++t) {
        const int cur = t & 1;
        const float x = ev[t];                 // LDS broadcast
        float a0 = fmaf(wx, x, bias), a1 = 0.f, a2 = 0.f, a3 = 0.f;
        const float4* h4 = reinterpret_cast<const float4*>(h[cur]);
        #pragma unroll
        for (int k = 0; k < HN / 4; ++k) {
            float4 hv = h4[k];                 // same addr all lanes -> broadcast
            a0 = fmaf(w[4*k+0], hv.x, a0);
            a1 = fmaf(w[4*k+1], hv.y, a1);
            a2 = fmaf(w[4*k+2], hv.z, a2);
            a3 = fmaf(w[4*k+3], hv.w, a3);
        }
        h[cur ^ 1][i] = fast_tanh((a0 + a1) + (a2 + a3));
        __syncthreads();                       // single barrier: dbuf makes W/R safe
    }

    // Tail: U[p][i] = h1 . W_ih2_row_i + b_ih2[i] + b_hh2[i]  (hoisted out of net2)
    {
        const float4* h4 = reinterpret_cast<const float4*>(h[len & 1]);
        const float4* w2 = reinterpret_cast<const float4*>(W_ih2 + i * HN);
        float a0 = b_ih2[i] + b_hh2[i], a1 = 0.f, a2 = 0.f, a3 = 0.f;
        #pragma unroll
        for (int k = 0; k < HN / 4; ++k) {
            float4 hv = h4[k];
            float4 wv = w2[k];
            a0 = fmaf(wv.x, hv.x, a0);
            a1 = fmaf(wv.y, hv.y, a1);
            a2 = fmaf(wv.z, hv.z, a2);
            a3 = fmaf(wv.w, hv.w, a3);
        }
        U[p * HN + i] = (a0 + a1) + (a2 + a3); // coalesced
    }
}

__global__ __launch_bounds__(256) void net2_kernel(
    const float* __restrict__ U,
    const float* __restrict__ W_hh2,
    float* __restrict__ out)
{
    const int tid  = threadIdx.x;
    const int wv   = tid >> 6;                 // wave 0..3
    const int lane = tid & 63;
    const int jg   = lane & 7;                 // inner group: h slice [jg*16, jg*16+16)
    const int ogl  = lane >> 3;                // output group within wave: 0..7
    const int og   = (wv << 3) + ogl;          // output group 0..31 (4 outputs each)
    const int rot  = jg >> 1;                  // bank-decorrelation rotation 0..3

    // After reduce-scatter this lane holds output og*4 + cidx (pairs jg, jg^1 dup).
    const int cidx = ((jg >> 2) & 1) * 2 + ((jg >> 1) & 1);
    const int oi_w = og * 4 + cidx;

    __shared__ float h[2][HN];                 // double-buffered hidden state

    // Weights w[c][4t+e] = W_hh2[og*4+c][jg*16 + 4*((t+rot)&3) + e]: the read
    // rotation is baked into the LOAD order so FMA reg indices stay static.
    float w[4][16];
    #pragma unroll
    for (int c = 0; c < 4; ++c) {
        const float* row = W_hh2 + (og * 4 + c) * HN + jg * 16;
        #pragma unroll
        for (int t = 0; t < 4; ++t) {
            const int krot = (t + rot) & 3;
            float4 v = *reinterpret_cast<const float4*>(row + 4 * krot);
            w[c][4*t+0] = v.x; w[c][4*t+1] = v.y;
            w[c][4*t+2] = v.z; w[c][4*t+3] = v.w;
        }
    }

    if (tid < HN) h[0][tid] = 0.0f;
    __syncthreads();

    const float* Up = U + oi_w;                // per-lane U column (dup pairs)
    float u0 = Up[0];                          // 2-deep prefetch pipe
    float u1 = Up[HN];

    for (int p = 0; p < PN; ++p) {
        const int cur = p & 1;
        const float u_cur = u0;
        u0 = u1;
        const int pn = (p + 2 < PN) ? (p + 2) : (PN - 1);
        u1 = Up[pn * HN];                      // issued 2 steps ahead of use

        // 4 b128 reads of this lane's 16-float h slice, rotated order:
        // slot t reads words jg*16 + 4*((t+rot)&3) -> 8 unique addrs spread
        // over disjoint bank quads -> conflict-free. Each read feeds 4 FMAs.
        const float* base = &h[cur][jg * 16];
        float s0 = 0.f, s1 = 0.f, s2 = 0.f, s3 = 0.f;
        #pragma unroll
        for (int t = 0; t < 4; ++t) {
            const int krot = (t + rot) & 3;    // runtime only in the ADDRESS
            float4 hv = *reinterpret_cast<const float4*>(base + 4 * krot);
            s0 = fmaf(w[0][4*t+0], hv.x, s0); s0 = fmaf(w[0][4*t+1], hv.y, s0);
            s0 = fmaf(w[0][4*t+2], hv.z, s0); s0 = fmaf(w[0][4*t+3], hv.w, s0);
            s1 = fmaf(w[1][4*t+0], hv.x, s1); s1 = fmaf(w[1][4*t+1], hv.y, s1);
            s1 = fmaf(w[1][4*t+2], hv.z, s1); s1 = fmaf(w[1][4*t+3], hv.w, s1);
            s2 = fmaf(w[2][4*t+0], hv.x, s2); s2 = fmaf(w[2][4*t+1], hv.y, s2);
            s2 = fmaf(w[2][4*t+2], hv.z, s2); s2 = fmaf(w[2][4*t+3], hv.w, s2);
            s3 = fmaf(w[3][4*t+0], hv.x, s3); s3 = fmaf(w[3][4*t+1], hv.y, s3);
            s3 = fmaf(w[3][4*t+2], hv.z, s3); s3 = fmaf(w[3][4*t+3], hv.w, s3);
        }

        // Reduce-scatter over the 8 jg lanes (lane bits 0..2): each stage keeps
        // half the accumulators and ships the other half to the partner.
        const bool lo4 = (jg & 4) == 0;
        float x0 = lo4 ? s0 : s2, x1 = lo4 ? s1 : s3;
        float y0 = lo4 ? s2 : s0, y1 = lo4 ? s3 : s1;
        x0 += __shfl_xor(x0 * 0.f + y0, 4) * 0.f + __shfl_xor(y0, 4) * 0.f + __shfl_xor(y0, 4); // (kept simple below)
        x0 = (lo4 ? s0 : s2) + __shfl_xor(y0, 4);
        x1 = (lo4 ? s1 : s3) + __shfl_xor(y1, 4);
        const bool lo2 = (jg & 2) == 0;
        float z  = lo2 ? x0 : x1;
        float zp = lo2 ? x1 : x0;
        z += __shfl_xor(zp, 2);
        z += __shfl_xor(z, 1);                 // full sum; pairs jg, jg^1 duplicate

        const float hn = fast_tanh(z + u_cur);
        if ((jg & 1) == 0) h[cur ^ 1][oi_w] = hn;  // 16 lanes/wave, distinct banks
        __syncthreads();                       // single barrier: dbuf makes W/R safe
    }

    if (tid < HN) out[tid] = h[PN & 1][tid];   // PN even -> result in h[0]
}

extern "C" void kernel_launch(void* const* d_in, const int* in_sizes, int n_in,
                              void* d_out, int out_size, void* d_ws, size_t ws_size,
                              hipStream_t stream)
{
    const float* event   = (const float*)d_in[0];
    const int*   lengths = (const int*)  d_in[1];
    const float* W_ih1   = (const float*)d_in[2];
    const float* W_hh1   = (const float*)d_in[3];
    const float* b_ih1   = (const float*)d_in[4];
    const float* b_hh1   = (const float*)d_in[5];
    const float* W_ih2   = (const float*)d_in[6];
    const float* W_hh2   = (const float*)d_in[7];
    const float* b_ih2   = (const float*)d_in[8];
    const float* b_hh2   = (const float*)d_in[9];
    float* out = (float*)d_out;                // 128 floats
    float* U   = (float*)d_ws;                 // PN*HN floats = 2 MB scratch

    hipLaunchKernelGGL(net1_kernel, dim3(PN), dim3(HN), 0, stream,
                       event, lengths, W_ih1, W_hh1, b_ih1, b_hh1,
                       W_ih2, b_ih2, b_hh2, U);
    hipLaunchKernelGGL(net2_kernel, dim3(1), dim3(256), 0, stream,
                       U, W_hh2, out);
}